// Round 1
// baseline (2749.135 us; speedup 1.0000x reference)
//
#include <hip/hip_runtime.h>

// VanillaRNN: BATCH=1024, SEQ=512, HID=512, OUT=10
// h[H,B] <- tanh(W_hx @ x_t + W_hh @ h + b_h), 512 sequential steps, then
// out[B,O] = (W_yh @ h + b_y)^T.
//
// Round 1: multi-launch baseline. One step_kernel per timestep (graph
// captures all 512). 256 WGs: 32 batch-groups (32 cols) x 8 h-groups (64
// rows). fp16 MFMA 16x16x32, fp32 accumulate, fp32 tanh epilogue.
// W_hh pre-converted once to fp16 A-fragment layout for coalesced loads.
// h ping-pongs between two fp16 [B][H] buffers in d_ws.
//
// ws layout: [0,1MB) hA | [1MB,2MB) hB | [2MB,2.5MB) W-frags. (ws poisoned
// 0xAA before every call: hA memset here, hB/frags fully overwritten.)

#define BATCH 1024
#define SEQT  512
#define HID   512
#define OUTD  10

typedef _Float16 f16;
typedef _Float16 f16x8 __attribute__((ext_vector_type(8)));
typedef _Float16 f16x4 __attribute__((ext_vector_type(4)));
typedef float    f32x4 __attribute__((ext_vector_type(4)));

// Convert W_hh fp32 [H][H] row-major into fp16 A-fragment layout:
// frag entry index = ((g*4+mt)*16+kk)*64 + lane, each entry = f16x8,
// holding A[m][k], m = g*64+mt*16+(lane&15), k = kk*32+(lane>>4&3)*8+j.
// (A-operand layout for mfma_f32_16x16x32: A[m=lane&15][k=(lane>>4)*8+j])
__global__ void wconv_kernel(const float* __restrict__ Whh, f16* __restrict__ frag) {
    int id = blockIdx.x * blockDim.x + threadIdx.x;   // 0..32767
    int lane = id & 63;
    int kk   = (id >> 6) & 15;
    int mt   = (id >> 10) & 3;
    int g    = id >> 12;
    int m = g * 64 + mt * 16 + (lane & 15);
    int k = kk * 32 + ((lane >> 4) & 3) * 8;
    const float* src = Whh + (size_t)m * HID + k;
    f16x8 v;
#pragma unroll
    for (int j = 0; j < 8; ++j) v[j] = (f16)src[j];
    *(f16x8*)(frag + (size_t)id * 8) = v;
}

__device__ __forceinline__ float fast_tanh(float v) {
    v = fminf(fmaxf(v, -15.f), 15.f);
    float e = __expf(2.f * v);
    return (e - 1.f) * __builtin_amdgcn_rcpf(e + 1.f);
}

// One timestep: hOut[b][i] = tanh(sum_j Whh[i][j]*hIn[b][j] + Whx[i]*x[b][t] + bh[i])
// Grid: 256 WGs x 256 thr. WG (g = wg&7, bg = wg>>3): rows [g*64,+64), cols [bg*32,+32).
// Waves: mhalf = wave&1 (32 rows), nhalf = wave>>1 (16 cols). 2 C-tiles/wave.
__global__ __launch_bounds__(256) void step_kernel(
    const f16* __restrict__ frag,   // W_hh fp16 fragments
    const f16* __restrict__ hIn,    // [B][H] fp16
    f16* __restrict__ hOut,         // [B][H] fp16
    const float* __restrict__ x,    // [B][T]
    const float* __restrict__ Whx,  // [H]
    const float* __restrict__ bh,   // [H]
    int t)
{
    __shared__ f16 hS[32][520];   // 32 batch cols x 512 hidden (+8 pad: 2-way-only banks)

    int tid = threadIdx.x;
    int wg  = blockIdx.x;
    int g   = wg & 7;
    int b0  = (wg >> 3) * 32;

    // Stage hIn tile [32 x 512] fp16 -> LDS (coalesced 16B loads)
    {
        int r = tid >> 3;      // 0..31 local batch row
        int c = tid & 7;       // chunk id
        const f16* src = hIn + (size_t)(b0 + r) * HID;
#pragma unroll
        for (int i = 0; i < 8; ++i) {
            int c8 = c + i * 8;                      // 0..63, 8 f16 each
            *(f16x8*)&hS[r][c8 * 8] = *(const f16x8*)(src + c8 * 8);
        }
    }
    __syncthreads();

    int wave  = tid >> 6;
    int lane  = tid & 63;
    int mhalf = wave & 1;
    int nhalf = wave >> 1;
    int ln15  = lane & 15;
    int q     = lane >> 4;

    f32x4 acc0 = {0.f, 0.f, 0.f, 0.f};
    f32x4 acc1 = {0.f, 0.f, 0.f, 0.f};
    const f16x8* A = (const f16x8*)frag;
    int mtb  = g * 4 + mhalf * 2;          // first of 2 M-tiles for this wave
    int nrow = nhalf * 16 + ln15;          // B-frag: n = lane&15 (local batch col)

#pragma unroll
    for (int kk = 0; kk < 16; ++kk) {
        // B[k][n]: k = kk*32 + q*8 + j, n = nrow  -> contiguous 16B in hS
        f16x8 bfrag = *(const f16x8*)&hS[nrow][kk * 32 + q * 8];
        f16x8 a0 = A[((mtb + 0) * 16 + kk) * 64 + lane];
        f16x8 a1 = A[((mtb + 1) * 16 + kk) * 64 + lane];
        acc0 = __builtin_amdgcn_mfma_f32_16x16x32_f16(a0, bfrag, acc0, 0, 0, 0);
        acc1 = __builtin_amdgcn_mfma_f32_16x16x32_f16(a1, bfrag, acc1, 0, 0, 0);
    }

    // Epilogue. C layout: col = lane&15 (n), row = q*4 + r (m).
    int b = b0 + nhalf * 16 + ln15;
    float xv = x[(size_t)b * SEQT + t];
#pragma unroll
    for (int mt = 0; mt < 2; ++mt) {
        f32x4 acc = mt ? acc1 : acc0;
        int m0 = g * 64 + (mhalf * 2 + mt) * 16 + q * 4;
        f16x4 hv;
#pragma unroll
        for (int r = 0; r < 4; ++r) {
            float pre = acc[r] + Whx[m0 + r] * xv + bh[m0 + r];
            hv[r] = (f16)fast_tanh(pre);
        }
        *(f16x4*)(hOut + (size_t)b * HID + m0) = hv;   // 8B store, m0 % 4 == 0
    }
}

// out[b*10+o] = b_y[o] + sum_k Wyh[o][k] * h[b][k]
__global__ __launch_bounds__(256) void y_kernel(
    const f16* __restrict__ h, const float* __restrict__ Wyh,
    const float* __restrict__ by, float* __restrict__ out)
{
    int id = blockIdx.x * blockDim.x + threadIdx.x;
    if (id >= BATCH * OUTD) return;
    int b = id / OUTD, o = id % OUTD;
    const f16*   hrow = h + (size_t)b * HID;
    const float* wrow = Wyh + (size_t)o * HID;
    float s = by[o];
#pragma unroll 8
    for (int k = 0; k < HID; ++k) s += wrow[k] * (float)hrow[k];
    out[id] = s;
}

extern "C" void kernel_launch(void* const* d_in, const int* in_sizes, int n_in,
                              void* d_out, int out_size, void* d_ws, size_t ws_size,
                              hipStream_t stream) {
    const float* x   = (const float*)d_in[0];
    const float* Whx = (const float*)d_in[1];
    const float* Whh = (const float*)d_in[2];
    const float* Wyh = (const float*)d_in[3];
    const float* bh  = (const float*)d_in[4];
    const float* by  = (const float*)d_in[5];
    float* out = (float*)d_out;

    char* ws  = (char*)d_ws;
    f16* hA   = (f16*)ws;                      // 1 MB
    f16* hB   = (f16*)(ws + (1 << 20));        // 1 MB
    f16* frag = (f16*)(ws + (2 << 20));        // 512 KB

    // h0 = 0 (ws is re-poisoned before every call)
    hipMemsetAsync(hA, 0, (size_t)BATCH * HID * sizeof(f16), stream);
    wconv_kernel<<<128, 256, 0, stream>>>(Whh, frag);

    for (int t = 0; t < SEQT; ++t) {
        const f16* hi = (t & 1) ? hB : hA;
        f16*       ho = (t & 1) ? hA : hB;
        step_kernel<<<256, 256, 0, stream>>>(frag, hi, ho, x, Whx, bh, t);
    }
    // T=512 even: last write (t=511, odd) went to hA
    y_kernel<<<(BATCH * OUTD + 255) / 256, 256, 0, stream>>>(hA, Wyh, by, out);
}